// Round 1
// baseline (34.948 us; speedup 1.0000x reference)
//
#include <hip/hip_runtime.h>
#include <hip/hip_bf16.h>

// ---------------------------------------------------------------------------
// VQC_Net: probs[b, c] = ( sum_j U[c][j] * amp[b][j] )^2,  c = 0..9
//   U = RY2 * D * RY1   (16x16, theta-only)
//   RY1[k][j] = prod_q ry(th_q)[k_q][j_q],  k_q = (k>>q)&1  (kron little-endian)
//   RY2[i][k] = prod_q ry(th_{4+q})[i_q][k_q]
//   D[k] = (-1)^(b0b1 + b1b2 + b2b3 + b0b3)
//   amp[0][k]  = prod_j ( (k>>j)&1 ? x0j : 1-x0j )                 (no sqrt)
//   amp[b][k]  = sqrt( prod_j ( (k>>(3-j))&1 ? xj^2 : 1-xj^2 ) )   (b >= 1)
// ---------------------------------------------------------------------------

__device__ __forceinline__ float ry_el(float c, float s, int i, int j) {
    // ry = [[c, -s], [s, c]]
    return (i == j) ? c : (i ? s : -s);
}

// One small kernel: T[c*16+j] = U[c][j] for c in 0..9 (160 floats into d_ws).
__global__ void build_T(const float* __restrict__ theta, float* __restrict__ T) {
    int t = threadIdx.x;
    if (t >= 160) return;
    int c = t >> 4;   // output class (row of U)
    int j = t & 15;   // input amp index (col of U)

    float co1[4], si1[4], co2[4], si2[4];
#pragma unroll
    for (int q = 0; q < 4; ++q) {
        float h1 = 0.5f * theta[q];
        float h2 = 0.5f * theta[4 + q];
        co1[q] = cosf(h1); si1[q] = sinf(h1);
        co2[q] = cosf(h2); si2[q] = sinf(h2);
    }

    float acc = 0.0f;
#pragma unroll
    for (int k = 0; k < 16; ++k) {
        int k0 = k & 1, k1 = (k >> 1) & 1, k2 = (k >> 2) & 1, k3 = (k >> 3) & 1;
        // R2[c][k]
        float r2 = ry_el(co2[0], si2[0], c & 1, k0)
                 * ry_el(co2[1], si2[1], (c >> 1) & 1, k1)
                 * ry_el(co2[2], si2[2], (c >> 2) & 1, k2)
                 * ry_el(co2[3], si2[3], (c >> 3) & 1, k3);
        // R1[k][j]
        float r1 = ry_el(co1[0], si1[0], k0, j & 1)
                 * ry_el(co1[1], si1[1], k1, (j >> 1) & 1)
                 * ry_el(co1[2], si1[2], k2, (j >> 2) & 1)
                 * ry_el(co1[3], si1[3], k3, (j >> 3) & 1);
        int sgn = (k0 & k1) ^ (k1 & k2) ^ (k2 & k3) ^ (k0 & k3);
        float d = sgn ? -1.0f : 1.0f;
        acc = fmaf(r2 * d, r1, acc);
    }
    T[t] = acc;
}

__global__ __launch_bounds__(256) void vqc_main(const float4* __restrict__ x,
                                                const float* __restrict__ T,
                                                float* __restrict__ out,
                                                int nsamp) {
    __shared__ float sOut[2560];  // 256 samples x 10 outputs, staged for coalesced flush

    int tid = threadIdx.x;
    long long b = (long long)blockIdx.x * 256 + tid;

    if (b < nsamp) {
        float4 xv = x[b];
        float amp[16];

        if (b == 0) {
            // little-endian bits, raw products, no sqrt
            float f0a = 1.0f - xv.x, f0b = xv.x;
            float f1a = 1.0f - xv.y, f1b = xv.y;
            float f2a = 1.0f - xv.z, f2b = xv.z;
            float f3a = 1.0f - xv.w, f3b = xv.w;
            // lo[l]: bit0->f0, bit1->f1 ; hi[h]: bit0->f2, bit1->f3
            float lo[4] = { f0a * f1a, f0b * f1a, f0a * f1b, f0b * f1b };
            float hi[4] = { f2a * f3a, f2b * f3a, f2a * f3b, f2b * f3b };
#pragma unroll
            for (int k = 0; k < 16; ++k)
                amp[k] = lo[k & 3] * hi[k >> 2];
        } else {
            // big-endian bits, squared probs, sqrt
            float p0 = xv.x * xv.x, p1 = xv.y * xv.y;
            float p2 = xv.z * xv.z, p3 = xv.w * xv.w;
            float f0a = 1.0f - p0, f0b = p0;
            float f1a = 1.0f - p1, f1b = p1;
            float f2a = 1.0f - p2, f2b = p2;
            float f3a = 1.0f - p3, f3b = p3;
            // hi[h]: h = k>>2, h bit1 -> f0 (k bit3), h bit0 -> f1 (k bit2)
            float hi[4] = { f0a * f1a, f0a * f1b, f0b * f1a, f0b * f1b };
            // lo[l]: l = k&3, l bit1 -> f2 (k bit1), l bit0 -> f3 (k bit0)
            float lo[4] = { f2a * f3a, f2a * f3b, f2b * f3a, f2b * f3b };
#pragma unroll
            for (int k = 0; k < 16; ++k)
                amp[k] = sqrtf(hi[k >> 2] * lo[k & 3]);
        }

        // 10x16 matvec. T is wave-uniform -> scalar loads (s_load) feed
        // v_fmac_f32 directly as the single allowed SGPR operand.
        // unroll 2 keeps ~32 live T-SGPRs (full unroll would want 160).
#pragma unroll 2
        for (int c = 0; c < 10; ++c) {
            float s = 0.0f;
#pragma unroll
            for (int jj = 0; jj < 16; ++jj)
                s = fmaf(T[c * 16 + jj], amp[jj], s);
            sOut[tid * 10 + c] = s * s;
        }
    }
    __syncthreads();

    long long blockStart = (long long)blockIdx.x * 256;
    long long remain = (long long)nsamp - blockStart;
    if (remain >= 256) {
        // full block: 2560 contiguous floats, base is 16B-aligned (blockStart*40 bytes)
        float4* ov = (float4*)(out + blockStart * 10);
        const float4* sv = (const float4*)sOut;
#pragma unroll
        for (int i = tid; i < 640; i += 256)
            ov[i] = sv[i];
    } else if (remain > 0) {
        int n = (int)remain * 10;
        for (int i = tid; i < n; i += 256)
            out[blockStart * 10 + i] = sOut[i];
    }
}

extern "C" void kernel_launch(void* const* d_in, const int* in_sizes, int n_in,
                              void* d_out, int out_size, void* d_ws, size_t ws_size,
                              hipStream_t stream) {
    const float* x = (const float*)d_in[0];      // [B,4] f32
    const float* theta = (const float*)d_in[1];  // [8]   f32
    float* out = (float*)d_out;                  // [B,10] f32
    float* T = (float*)d_ws;                     // 160 floats scratch

    int nsamp = in_sizes[0] / 4;

    build_T<<<1, 192, 0, stream>>>(theta, T);

    int blocks = (nsamp + 255) / 256;
    vqc_main<<<blocks, 256, 0, stream>>>((const float4*)x, T, out, nsamp);
}